// Round 1
// baseline (433.236 us; speedup 1.0000x reference)
//
#include <hip/hip_runtime.h>
#include <hip/hip_bf16.h>

// GCNLayer: 2 SpMM hops (CSR-built on device, atomic-free aggregate) +
// 3 fused fp32 tiled GEMMs with bias+relu epilogue.
// Layout: out[r*1536 + hop*512 + c].

#define IN_DIM 512
#define OUT_DIM 512

// ---------------- CSR build ----------------

__global__ __launch_bounds__(256) void hist_kernel(const int* __restrict__ dst,
                                                   int* __restrict__ counts, int E) {
    int e = blockIdx.x * blockDim.x + threadIdx.x;
    if (e < E) atomicAdd(&counts[dst[e]], 1);
}

// single block, 1024 threads: exclusive scan of counts[0..n) -> offs[0..n]
// also copies to cursor[0..n)
__global__ __launch_bounds__(1024) void scan_kernel(const int* __restrict__ counts,
                                                    int* __restrict__ offs,
                                                    int* __restrict__ cursor, int n) {
    __shared__ int partials[16];
    const int tid = threadIdx.x;
    const int chunk = (n + 1023) / 1024;
    const int start = tid * chunk;
    const int end = min(start + chunk, n);

    int sum = 0;
    for (int i = start; i < end; ++i) sum += counts[i];

    // inclusive scan within wave (64 lanes)
    const int lane = tid & 63;
    const int wave = tid >> 6;
    int v = sum;
    #pragma unroll
    for (int d = 1; d < 64; d <<= 1) {
        int up = __shfl_up(v, d, 64);
        if (lane >= d) v += up;
    }
    if (lane == 63) partials[wave] = v;
    __syncthreads();
    if (tid == 0) {
        int acc = 0;
        #pragma unroll
        for (int w = 0; w < 16; ++w) { int t = partials[w]; partials[w] = acc; acc += t; }
    }
    __syncthreads();

    int run = partials[wave] + (v - sum);  // exclusive prefix of this thread
    for (int i = start; i < end; ++i) {
        offs[i] = run;
        cursor[i] = run;
        run += counts[i];
    }
    if (end == n) offs[n] = run;  // all threads past the data write the same total
}

__global__ __launch_bounds__(256) void scatter_kernel(const int* __restrict__ src,
                                                      const int* __restrict__ dst,
                                                      const float* __restrict__ edge_w,
                                                      int* __restrict__ cursor,
                                                      int* __restrict__ esrc,
                                                      float* __restrict__ eww, int E) {
    int e = blockIdx.x * blockDim.x + threadIdx.x;
    if (e < E) {
        int d = dst[e];
        int pos = atomicAdd(&cursor[d], 1);
        esrc[pos] = src[e];
        eww[pos] = edge_w[e];
    }
}

// ---------------- SpMM hop: hout[v] = D[v] * sum_{e: dst=v} w_e * hin[src_e] --------

__global__ __launch_bounds__(256) void hop_kernel(const float* __restrict__ hin,
                                                  const float* __restrict__ Dn,
                                                  const int* __restrict__ offs,
                                                  const int* __restrict__ esrc,
                                                  const float* __restrict__ eww,
                                                  float* __restrict__ hout) {
    const int v = blockIdx.x;
    const int t = threadIdx.x;  // 256 threads, float2 each -> 512 feats
    const int beg = offs[v];
    const int end = offs[v + 1];
    float ax = 0.f, ay = 0.f;
    for (int i = beg; i < end; ++i) {
        const int s = esrc[i];        // wave-uniform
        const float w = eww[i];       // wave-uniform
        const float2 x = *(const float2*)&hin[(size_t)s * IN_DIM + t * 2];
        ax = fmaf(x.x, w, ax);
        ay = fmaf(x.y, w, ay);
    }
    const float d = Dn[v];
    float2 r = {ax * d, ay * d};
    *(float2*)&hout[(size_t)v * IN_DIM + t * 2] = r;
}

// ---------------- fused GEMM + bias + relu ----------------
// C[r, hop*512+c] = relu(A_hop[r,:] @ W[hop][:,c] + b[hop][c])
// BM=BN=64, BK=16, 256 threads, 4x4 micro-tile.

#define GBM 64
#define GBN 64
#define GBK 16

__global__ __launch_bounds__(256) void gemm_bias_relu(const float* __restrict__ A0,
                                                      const float* __restrict__ A1,
                                                      const float* __restrict__ A2,
                                                      const float* __restrict__ Wt,
                                                      const float* __restrict__ bias,
                                                      float* __restrict__ out, int M) {
    const int hop = blockIdx.z;
    const float* __restrict__ A = (hop == 0) ? A0 : (hop == 1) ? A1 : A2;
    const float* __restrict__ B = Wt + (size_t)hop * IN_DIM * OUT_DIM;
    const float* __restrict__ bs = bias + hop * OUT_DIM;

    __shared__ __align__(16) float As[GBK][GBM + 4];  // +4: b128-aligned, kills conflicts
    __shared__ __align__(16) float Bs[GBK][GBN];

    const int tid = threadIdx.x;
    const int tx = tid & 15;   // micro col group
    const int ty = tid >> 4;   // micro row group
    const int row0 = blockIdx.x * GBM;
    const int col0 = blockIdx.y * GBN;

    // A load: float4 per thread; tid%4 = k-quad, tid/4 = row (0..63)
    const int a_kq = tid & 3;
    const int a_row = tid >> 2;
    // B load: float4 per thread; tid%16 = n-quad, tid/16 = k (0..15)
    const int b_nq = tid & 15;
    const int b_k = tid >> 4;

    float acc[4][4] = {};

    for (int k0 = 0; k0 < IN_DIM; k0 += GBK) {
        int gr = row0 + a_row;
        gr = gr < M ? gr : M - 1;  // clamp; invalid rows never stored
        const float4 av = *(const float4*)&A[(size_t)gr * IN_DIM + k0 + a_kq * 4];
        As[a_kq * 4 + 0][a_row] = av.x;
        As[a_kq * 4 + 1][a_row] = av.y;
        As[a_kq * 4 + 2][a_row] = av.z;
        As[a_kq * 4 + 3][a_row] = av.w;

        const float4 bv = *(const float4*)&B[(size_t)(k0 + b_k) * OUT_DIM + col0 + b_nq * 4];
        *(float4*)&Bs[b_k][b_nq * 4] = bv;

        __syncthreads();

        #pragma unroll
        for (int k = 0; k < GBK; ++k) {
            const float4 a4 = *(const float4*)&As[k][ty * 4];
            const float4 b4 = *(const float4*)&Bs[k][tx * 4];
            const float ar[4] = {a4.x, a4.y, a4.z, a4.w};
            const float br[4] = {b4.x, b4.y, b4.z, b4.w};
            #pragma unroll
            for (int i = 0; i < 4; ++i)
                #pragma unroll
                for (int j = 0; j < 4; ++j)
                    acc[i][j] = fmaf(ar[i], br[j], acc[i][j]);
        }
        __syncthreads();
    }

    #pragma unroll
    for (int i = 0; i < 4; ++i) {
        const int r = row0 + ty * 4 + i;
        if (r >= M) continue;
        #pragma unroll
        for (int j = 0; j < 4; ++j) {
            const int c = col0 + tx * 4 + j;
            float v = acc[i][j] + bs[c];
            out[(size_t)r * (3 * OUT_DIM) + hop * OUT_DIM + c] = v > 0.f ? v : 0.f;
        }
    }
}

// ---------------- launcher ----------------

extern "C" void kernel_launch(void* const* d_in, const int* in_sizes, int n_in,
                              void* d_out, int out_size, void* d_ws, size_t ws_size,
                              hipStream_t stream) {
    const float* features = (const float*)d_in[0];
    const float* D_norm   = (const float*)d_in[1];
    const float* edge_w   = (const float*)d_in[2];
    const float* W        = (const float*)d_in[3];
    const float* b        = (const float*)d_in[4];
    const int*   src      = (const int*)d_in[5];
    const int*   dst      = (const int*)d_in[6];
    const int N = in_sizes[1];   // D_norm is [N,1]
    const int E = in_sizes[2];
    float* out = (float*)d_out;

    char* w = (char*)d_ws;
    auto alloc = [&](size_t bytes) {
        void* p = (void*)w;
        w += (bytes + 255) & ~(size_t)255;
        return p;
    };
    int*   counts = (int*)alloc((size_t)N * 4);
    int*   offs   = (int*)alloc((size_t)(N + 1) * 4);
    int*   cursor = (int*)alloc((size_t)N * 4);
    int*   esrc   = (int*)alloc((size_t)E * 4);
    float* eww    = (float*)alloc((size_t)E * 4);
    float* h1     = (float*)alloc((size_t)N * IN_DIM * 4);
    float* h2     = (float*)alloc((size_t)N * IN_DIM * 4);

    hipMemsetAsync(counts, 0, (size_t)N * 4, stream);
    hist_kernel<<<(E + 255) / 256, 256, 0, stream>>>(dst, counts, E);
    scan_kernel<<<1, 1024, 0, stream>>>(counts, offs, cursor, N);
    scatter_kernel<<<(E + 255) / 256, 256, 0, stream>>>(src, dst, edge_w, cursor, esrc, eww, E);

    hop_kernel<<<N, 256, 0, stream>>>(features, D_norm, offs, esrc, eww, h1);
    hop_kernel<<<N, 256, 0, stream>>>(h1, D_norm, offs, esrc, eww, h2);

    dim3 grid((N + GBM - 1) / GBM, OUT_DIM / GBN, 3);
    gemm_bias_relu<<<grid, 256, 0, stream>>>(features, h1, h2, W, b, out, N);
}

// Round 3
// 290.570 us; speedup vs baseline: 1.4910x; 1.4910x over previous
//
#include <hip/hip_runtime.h>
#include <hip/hip_bf16.h>

// GCNLayer: CSR build + 2 SpMM hops (fp32) + 3 fused GEMMs via bf16 hi/lo
// split MFMA (3x v_mfma_f32_16x16x32_bf16 per fp32 product).
// out[r*1536 + hop*512 + c] = relu(h_hop @ W[hop] + b[hop])

#define IN_DIM 512
#define OUT_DIM 512

typedef float f32x4 __attribute__((ext_vector_type(4)));
typedef unsigned short u16x8 __attribute__((ext_vector_type(8)));

__device__ inline unsigned short f2bf(float x) {
    union { float f; unsigned u; } v; v.f = x;
    unsigned r = v.u + 0x7fff + ((v.u >> 16) & 1);   // round-to-nearest-even
    return (unsigned short)(r >> 16);
}
__device__ inline float bf2f(unsigned short h) {
    union { float f; unsigned u; } v; v.u = ((unsigned)h) << 16;
    return v.f;
}

__device__ inline void gld_lds16(const void* g, void* l) {
    __builtin_amdgcn_global_load_lds(
        (const __attribute__((address_space(1))) unsigned*)g,
        (__attribute__((address_space(3))) unsigned*)l, 16, 0, 0);
}

__device__ inline void mfma16(f32x4& d, u16x8 a, u16x8 b) {
    asm("v_mfma_f32_16x16x32_bf16 %0, %1, %2, %0" : "+v"(d) : "v"(a), "v"(b));
}

// ---------------- CSR build ----------------

__global__ __launch_bounds__(256) void hist_kernel(const int* __restrict__ dst,
                                                   int* __restrict__ counts, int E) {
    int e = blockIdx.x * blockDim.x + threadIdx.x;
    if (e < E) atomicAdd(&counts[dst[e]], 1);
}

__global__ __launch_bounds__(1024) void scan_kernel(const int* __restrict__ counts,
                                                    int* __restrict__ offs,
                                                    int* __restrict__ cursor, int n) {
    __shared__ int partials[16];
    const int tid = threadIdx.x;
    const int chunk = (n + 1023) / 1024;
    const int start = tid * chunk;
    const int end = min(start + chunk, n);

    int sum = 0;
    for (int i = start; i < end; ++i) sum += counts[i];

    const int lane = tid & 63;
    const int wave = tid >> 6;
    int v = sum;
    #pragma unroll
    for (int d = 1; d < 64; d <<= 1) {
        int up = __shfl_up(v, d, 64);
        if (lane >= d) v += up;
    }
    if (lane == 63) partials[wave] = v;
    __syncthreads();
    if (tid == 0) {
        int acc = 0;
        #pragma unroll
        for (int w = 0; w < 16; ++w) { int t = partials[w]; partials[w] = acc; acc += t; }
    }
    __syncthreads();

    int run = partials[wave] + (v - sum);
    for (int i = start; i < end; ++i) {
        offs[i] = run;
        cursor[i] = run;
        run += counts[i];
    }
    if (end == n) offs[n] = run;
}

__global__ __launch_bounds__(256) void scatter_kernel(const int* __restrict__ src,
                                                      const int* __restrict__ dst,
                                                      const float* __restrict__ edge_w,
                                                      int* __restrict__ cursor,
                                                      int* __restrict__ esrc,
                                                      float* __restrict__ eww, int E) {
    int e = blockIdx.x * blockDim.x + threadIdx.x;
    if (e < E) {
        int d = dst[e];
        int pos = atomicAdd(&cursor[d], 1);
        esrc[pos] = src[e];
        eww[pos] = edge_w[e];
    }
}

// ---------------- SpMM hop ----------------
// hout[v] = D[v] * sum_{e: dst=v} w_e * hin[src_e]; 128 thr x float4 = 512 feats

__global__ __launch_bounds__(128) void hop_kernel(const float* __restrict__ hin,
                                                  const float* __restrict__ Dn,
                                                  const int* __restrict__ offs,
                                                  const int* __restrict__ esrc,
                                                  const float* __restrict__ eww,
                                                  float* __restrict__ hout) {
    const int v = blockIdx.x;
    const int t = threadIdx.x;
    const int beg = offs[v];
    const int end = offs[v + 1];
    float ax = 0.f, ay = 0.f, az = 0.f, aw = 0.f;
    int sN = 0; float wN = 0.f;
    if (beg < end) { sN = esrc[beg]; wN = eww[beg]; }
    for (int i = beg; i < end; ++i) {
        const int s = sN;
        const float w = wN;
        if (i + 1 < end) { sN = esrc[i + 1]; wN = eww[i + 1]; }  // prefetch (uniform)
        const float4 x = *(const float4*)&hin[(size_t)s * IN_DIM + t * 4];
        ax = fmaf(x.x, w, ax);
        ay = fmaf(x.y, w, ay);
        az = fmaf(x.z, w, az);
        aw = fmaf(x.w, w, aw);
    }
    const float d = Dn[v];
    float4 r = {ax * d, ay * d, az * d, aw * d};
    *(float4*)&hout[(size_t)v * IN_DIM + t * 4] = r;
}

// ---------------- W transpose + bf16 hi/lo split (once per launch) ----------
// W[hop][k][n] fp32 -> WtHi/WtLo[hop][n][k] bf16

__global__ __launch_bounds__(256) void wsplit_kernel(const float* __restrict__ W,
                                                     unsigned short* __restrict__ WtHi,
                                                     unsigned short* __restrict__ WtLo) {
    const int t = blockIdx.x * 256 + threadIdx.x;   // 3*512*128 total
    const int kq = t & 127;
    const int n = (t >> 7) & 511;
    const int h = t >> 16;
    const float* w = W + (size_t)h * IN_DIM * OUT_DIM;
    unsigned short hi[4], lo[4];
    #pragma unroll
    for (int j = 0; j < 4; ++j) {
        const float x = w[(size_t)(kq * 4 + j) * OUT_DIM + n];
        hi[j] = f2bf(x);
        lo[j] = f2bf(x - bf2f(hi[j]));
    }
    const size_t o = (size_t)h * IN_DIM * OUT_DIM + (size_t)n * IN_DIM + kq * 4;
    *(ushort4*)&WtHi[o] = *(const ushort4*)hi;
    *(ushort4*)&WtLo[o] = *(const ushort4*)lo;
}

// ---------------- split-bf16 MFMA GEMM + bias + relu ----------------
// BM=BN=128, BK=32, 256 thr (4 waves, 2x2 of 64x64), single-buffer LDS.

#define BM 128
#define BN 128
#define BK 32

__global__ __launch_bounds__(256) void gemm_split_mfma(
        const float* __restrict__ A0, const float* __restrict__ A1,
        const float* __restrict__ A2,
        const unsigned short* __restrict__ WtHi, const unsigned short* __restrict__ WtLo,
        const float* __restrict__ bias, float* __restrict__ out, int M) {

    __shared__ unsigned short Ahi[BM * BK];   // 8 KB each, row stride 64 B
    __shared__ unsigned short Alo[BM * BK];
    __shared__ unsigned short Bhi[BN * BK];
    __shared__ unsigned short Blo[BN * BK];

    const int tid = threadIdx.x;
    const int ln = tid & 63;
    const int wv = tid >> 6;
    const int hop = blockIdx.z;
    const float* __restrict__ A = hop == 0 ? A0 : hop == 1 ? A1 : A2;
    const unsigned short* __restrict__ BH = WtHi + (size_t)hop * IN_DIM * OUT_DIM;
    const unsigned short* __restrict__ BL = WtLo + (size_t)hop * IN_DIM * OUT_DIM;

    const int row0 = blockIdx.x * BM;
    const int col0 = blockIdx.y * BN;

    // A reg-stage mapping: thread -> (row=tid>>3 (+32p), 4-float k-chunk kq=tid&7)
    const int ar = tid >> 3;
    const int akq = tid & 7;
    // B DMA mapping: wave wv stages chunks {2wv, 2wv+1}; lane -> (row, 16B slot)
    const int bi = ln >> 2;
    const int bsl = ln & 3;

    const int wm = wv >> 1, wn = wv & 1;   // wave's 64x64 sub-tile
    const int fr = ln & 15, kg = ln >> 4;  // fragment row/col + k-group

    f32x4 acc[4][4] = {};

    for (int kt = 0; kt < IN_DIM / BK; ++kt) {
        const int k0 = kt * BK;

        // B tiles: global_load_lds, source pre-swizzled (linear LDS dest)
        #pragma unroll
        for (int q = 0; q < 2; ++q) {
            const int nrow = (wv * 2 + q) * 16 + bi;          // 0..127
            const int kp = bsl ^ ((nrow >> 1) & 3);           // swizzled 16B slot
            const size_t go = (size_t)(col0 + nrow) * IN_DIM + k0 + kp * 8;
            gld_lds16(BH + go, (char*)Bhi + (wv * 2 + q) * 1024);
            gld_lds16(BL + go, (char*)Blo + (wv * 2 + q) * 1024);
        }

        // A tile: fp32 load + hi/lo split + swizzled ds_write_b64
        #pragma unroll
        for (int p = 0; p < 4; ++p) {
            const int r = ar + p * 32;                        // 0..127
            int gr = row0 + r;
            gr = gr < M ? gr : M - 1;                         // clamp; never stored
            const float4 av = *(const float4*)&A[(size_t)gr * IN_DIM + k0 + akq * 4];
            unsigned short h[4], l[4];
            h[0] = f2bf(av.x); l[0] = f2bf(av.x - bf2f(h[0]));
            h[1] = f2bf(av.y); l[1] = f2bf(av.y - bf2f(h[1]));
            h[2] = f2bf(av.z); l[2] = f2bf(av.z - bf2f(h[2]));
            h[3] = f2bf(av.w); l[3] = f2bf(av.w - bf2f(h[3]));
            const int boff = r * 64 + ((akq * 8) ^ ((((r >> 1) & 3)) << 4));
            *(ushort4*)((char*)Ahi + boff) = *(const ushort4*)h;
            *(ushort4*)((char*)Alo + boff) = *(const ushort4*)l;
        }

        __syncthreads();   // drains vmcnt (DMA) + lgkmcnt (ds_write)

        u16x8 ah[4], al[4], bh[4], bl[4];
        #pragma unroll
        for (int mf = 0; mf < 4; ++mf) {
            const int r = wm * 64 + mf * 16 + fr;
            const int off = r * 64 + ((kg * 16) ^ ((((r >> 1) & 3)) << 4));
            ah[mf] = *(const u16x8*)((const char*)Ahi + off);
            al[mf] = *(const u16x8*)((const char*)Alo + off);
        }
        #pragma unroll
        for (int nf = 0; nf < 4; ++nf) {
            const int n = wn * 64 + nf * 16 + fr;
            const int off = n * 64 + ((kg * 16) ^ ((((n >> 1) & 3)) << 4));
            bh[nf] = *(const u16x8*)((const char*)Bhi + off);
            bl[nf] = *(const u16x8*)((const char*)Blo + off);
        }

        // 3 passes of 16 MFMAs: dep distance 16 on each acc register set
        #pragma unroll
        for (int mf = 0; mf < 4; ++mf)
            #pragma unroll
            for (int nf = 0; nf < 4; ++nf)
                mfma16(acc[mf][nf], al[mf], bh[nf]);
        #pragma unroll
        for (int mf = 0; mf < 4; ++mf)
            #pragma unroll
            for (int nf = 0; nf < 4; ++nf)
                mfma16(acc[mf][nf], ah[mf], bl[nf]);
        #pragma unroll
        for (int mf = 0; mf < 4; ++mf)
            #pragma unroll
            for (int nf = 0; nf < 4; ++nf)
                mfma16(acc[mf][nf], ah[mf], bh[nf]);

        __syncthreads();   // WAR: all reads done before next-tile staging
    }

    asm volatile("s_nop 7\n\ts_nop 7" ::: );   // MFMA->VALU read hazard guard

    const int rb = row0 + wm * 64;
    const int cb = col0 + wn * 64;
    #pragma unroll
    for (int nf = 0; nf < 4; ++nf) {
        const int c = cb + nf * 16 + fr;                 // C/D: col = lane&15
        const float bv = bias[hop * OUT_DIM + c];
        #pragma unroll
        for (int mf = 0; mf < 4; ++mf) {
            #pragma unroll
            for (int j = 0; j < 4; ++j) {
                const int r = rb + mf * 16 + kg * 4 + j; // C/D: row = (lane>>4)*4+reg
                if (r < M) {
                    float v = acc[mf][nf][j] + bv;
                    out[(size_t)r * (3 * OUT_DIM) + hop * OUT_DIM + c] = v > 0.f ? v : 0.f;
                }
            }
        }
    }
}

// ---------------- launcher ----------------

extern "C" void kernel_launch(void* const* d_in, const int* in_sizes, int n_in,
                              void* d_out, int out_size, void* d_ws, size_t ws_size,
                              hipStream_t stream) {
    const float* features = (const float*)d_in[0];
    const float* D_norm   = (const float*)d_in[1];
    const float* edge_w   = (const float*)d_in[2];
    const float* W        = (const float*)d_in[3];
    const float* b        = (const float*)d_in[4];
    const int*   src      = (const int*)d_in[5];
    const int*   dst      = (const int*)d_in[6];
    const int N = in_sizes[1];   // D_norm is [N,1]
    const int E = in_sizes[2];
    float* out = (float*)d_out;

    char* w = (char*)d_ws;
    auto alloc = [&](size_t bytes) {
        void* p = (void*)w;
        w += (bytes + 255) & ~(size_t)255;
        return p;
    };
    int*            counts = (int*)alloc((size_t)N * 4);
    int*            offs   = (int*)alloc((size_t)(N + 1) * 4);
    int*            cursor = (int*)alloc((size_t)N * 4);
    int*            esrc   = (int*)alloc((size_t)E * 4);
    float*          eww    = (float*)alloc((size_t)E * 4);
    float*          h1     = (float*)alloc((size_t)N * IN_DIM * 4);
    float*          h2     = (float*)alloc((size_t)N * IN_DIM * 4);
    unsigned short* wthi   = (unsigned short*)alloc((size_t)3 * IN_DIM * OUT_DIM * 2);
    unsigned short* wtlo   = (unsigned short*)alloc((size_t)3 * IN_DIM * OUT_DIM * 2);

    hipMemsetAsync(counts, 0, (size_t)N * 4, stream);
    hist_kernel<<<(E + 255) / 256, 256, 0, stream>>>(dst, counts, E);
    scan_kernel<<<1, 1024, 0, stream>>>(counts, offs, cursor, N);
    scatter_kernel<<<(E + 255) / 256, 256, 0, stream>>>(src, dst, edge_w, cursor, esrc, eww, E);

    wsplit_kernel<<<(3 * IN_DIM * (OUT_DIM / 4)) / 256, 256, 0, stream>>>(W, wthi, wtlo);

    hop_kernel<<<N, 128, 0, stream>>>(features, D_norm, offs, esrc, eww, h1);
    hop_kernel<<<N, 128, 0, stream>>>(h1, D_norm, offs, esrc, eww, h2);

    dim3 grid((N + BM - 1) / BM, OUT_DIM / BN, 3);
    gemm_split_mfma<<<grid, 256, 0, stream>>>(features, h1, h2, wthi, wtlo, b, out, N);
}